// Round 3
// baseline (161.697 us; speedup 1.0000x reference)
//
#include <hip/hip_runtime.h>
#include <hip/hip_bf16.h>

// Problem constants
#define NB    8
#define CCH   64      // CIN = COUT = 64
#define HH    128
#define WW    128
#define KTAP  9
#define HW    (HH * WW)            // 16384
#define KSTEPS 18                  // 576 / 32

typedef _Float16 f16x8 __attribute__((ext_vector_type(8)));
typedef _Float16 f16x2 __attribute__((ext_vector_type(2)));
typedef __attribute__((ext_vector_type(4))) float f32x4;

// RNE f32 pair -> packed f16x2 (as uint)
__device__ inline unsigned int pack_f16(float a, float b) {
    f16x2 h;
    h[0] = (_Float16)a;   // v_cvt_f16_f32 (RNE)
    h[1] = (_Float16)b;
    return __builtin_bit_cast(unsigned int, h);
}

// ---------- K1: transpose x NCHW f32 -> xt NHWC f16  (blocks 0..2047)
//             + maxabs+quantize weights into MFMA B frags (block 2048)
__global__ __launch_bounds__(256) void prep_kernel(const float* __restrict__ x,
                                                   const float* __restrict__ w,
                                                   unsigned int* __restrict__ xt32,
                                                   uint4* __restrict__ bq) {
    __shared__ float tile[64 * 65];
    const int t = threadIdx.x;
    const int bid = blockIdx.x;

    if (bid < 2048) {
        // ---- transpose 64 channels x 64 pixels ----
        const int n = bid >> 8;
        const int pbase = (bid & 255) * 64;
        #pragma unroll
        for (int i = 0; i < 4; i++) {
            int idx = i * 256 + t;
            int c = idx >> 4, f4 = idx & 15;
            float4 v = *(const float4*)&x[((size_t)(n * CCH + c)) * HW + pbase + f4 * 4];
            float* d = &tile[c * 65 + f4 * 4];
            d[0] = v.x; d[1] = v.y; d[2] = v.z; d[3] = v.w;
        }
        __syncthreads();
        const int px = t >> 2, c4 = t & 3;
        float f[16];
        #pragma unroll
        for (int j = 0; j < 16; j++) f[j] = tile[(c4 * 16 + j) * 65 + px];
        unsigned int o8[8];
        #pragma unroll
        for (int i = 0; i < 8; i++) o8[i] = pack_f16(f[2 * i], f[2 * i + 1]);
        uint4* dst = (uint4*)&xt32[((size_t)(n * HW + pbase + px)) * 32 + c4 * 8];
        dst[0] = make_uint4(o8[0], o8[1], o8[2], o8[3]);
        dst[1] = make_uint4(o8[4], o8[5], o8[6], o8[7]);
    } else {
        // ---- weight maxabs + quant + swizzle to B-fragment order ----
        float m = 0.f;
        for (int i = t; i < CCH * CCH * KTAP; i += 256)
            m = fmaxf(m, fabsf(w[i]));
        #pragma unroll
        for (int off = 32; off > 0; off >>= 1)
            m = fmaxf(m, __shfl_down(m, off));
        if ((t & 63) == 0) tile[t >> 6] = m;
        __syncthreads();
        m = fmaxf(fmaxf(tile[0], tile[1]), fmaxf(tile[2], tile[3]));
        const float scale = fmaxf(m, 1e-8f) / 127.f;
        const float inv_scale = 1.f / scale;

        for (int rec = t; rec < 4608; rec += 256) {
            int nt  = rec / (KSTEPS * 64);
            int rem = rec - nt * (KSTEPS * 64);
            int s    = rem >> 6;
            int lane = rem & 63;
            int quad = lane >> 4, n16 = lane & 15;
            int o = nt * 16 + n16;
            unsigned int u[4];
            #pragma unroll
            for (int jj = 0; jj < 4; jj++) {
                float q[2];
                #pragma unroll
                for (int h = 0; h < 2; h++) {
                    int k   = s * 32 + quad * 8 + 2 * jj + h;
                    int c   = k & 63;
                    int tap = k >> 6;
                    float v  = w[(o * CCH + c) * KTAP + tap];
                    float qq = rintf(v * inv_scale);          // RNE = jnp.round
                    q[h] = fminf(fmaxf(qq, -128.f), 127.f) * scale;
                }
                u[jj] = pack_f16(q[0], q[1]);
            }
            bq[rec] = make_uint4(u[0], u[1], u[2], u[3]);
        }
    }
}

// ---------- K2: fused deformable-sample + MFMA GEMM ----------
// Block = 64 pixels x 64 out-channels; wave w = 16-out-channel slab.
__global__ __launch_bounds__(256) void deform_mfma(const unsigned short* __restrict__ xt,
                                                   const float* __restrict__ offset,
                                                   const uint4* __restrict__ bq,
                                                   float* __restrict__ out) {
    __shared__ uint4 SIdx[576];            // per (tap,px): 4 corner byte-offsets
    __shared__ uint2 SW[576];              // per (tap,px): packed f16 weights
    __shared__ _Float16 Abuf[2][64 * 64];  // double-buffered A tile, XOR-swizzled

    const int t    = threadIdx.x;
    const int wid  = t >> 6;
    const int lane = t & 63;
    const int quad = lane >> 4, n16 = lane & 15;
    const int bid  = blockIdx.x;
    const int n    = bid & 7;                 // image -> XCD swizzle
    const int px0  = (bid >> 3) * 64;
    const int pl   = t >> 2;                  // pixel within tile
    const int c4   = t & 3;                   // channel chunk id

    const char* xb = (const char*)(xt + (size_t)n * HW * CCH);
    const float* offn = offset + (size_t)n * 2 * KTAP * HW;

    // Preload this wave's B slab
    uint4 bfrag[KSTEPS];
    #pragma unroll
    for (int s = 0; s < KSTEPS; s++)
        bfrag[s] = bq[(wid * KSTEPS + s) * 64 + lane];

    // ---- setup: one task per (tap, pixel), all upfront ----
    for (int u = t; u < 576; u += 256) {
        const int tap = u >> 6, p = u & 63;
        const int ppx = px0 + p;
        const int ho = ppx >> 7, wo = ppx & 127;
        const int ky = tap / 3, kx = tap - 3 * ky;
        const float py  = (float)(ho - 1 + ky) + offn[(2 * tap) * HW + ppx];
        const float pxf = (float)(wo - 1 + kx) + offn[(2 * tap + 1) * HW + ppx];
        const float fy = floorf(py), fx = floorf(pxf);
        const int y0 = (int)fy, x0 = (int)fx;
        const float dy = py - fy, dx = pxf - fx;
        const int y1 = y0 + 1, x1 = x0 + 1;
        const bool vy0 = (y0 >= 0) && (y0 < HH);
        const bool vy1 = (y1 >= 0) && (y1 < HH);
        const bool vx0 = (x0 >= 0) && (x0 < WW);
        const bool vx1 = (x1 >= 0) && (x1 < WW);
        const int y0c = min(max(y0, 0), HH - 1);
        const int y1c = min(max(y1, 0), HH - 1);
        const int x0c = min(max(x0, 0), WW - 1);
        const int x1c = min(max(x1, 0), WW - 1);
        const float w00 = (1.f - dy) * (1.f - dx) * ((vy0 && vx0) ? 1.f : 0.f);
        const float w01 = (1.f - dy) * dx         * ((vy0 && vx1) ? 1.f : 0.f);
        const float w10 = dy * (1.f - dx)         * ((vy1 && vx0) ? 1.f : 0.f);
        const float w11 = dy * dx                 * ((vy1 && vx1) ? 1.f : 0.f);
        SIdx[u] = make_uint4((unsigned)((y0c * WW + x0c) * 128),
                             (unsigned)((y0c * WW + x1c) * 128),
                             (unsigned)((y1c * WW + x0c) * 128),
                             (unsigned)((y1c * WW + x1c) * 128));
        SW[u] = make_uint2(pack_f16(w00, w01), pack_f16(w10, w11));
    }

    f32x4 acc[4];
    #pragma unroll
    for (int mt = 0; mt < 4; mt++) acc[mt] = (f32x4){0.f, 0.f, 0.f, 0.f};

    // chunk A = channels [c4*8, +8), chunk B = channels [32+c4*8, +8):
    // both 16B loads land in the SAME 64B line per corner (halves L1 services).
    const int cb = c4 * 16;    // byte offset of chunk A within pixel row
    const int p7 = pl & 7;

    auto build = [&](int tap, int buf) {
        const uint4 ii = SIdx[tap * 64 + pl];
        const uint2 ww = SW[tap * 64 + pl];
        const f16x2 wA = __builtin_bit_cast(f16x2, ww.x);
        const f16x2 wB = __builtin_bit_cast(f16x2, ww.y);
        const f16x8 a00 = *(const f16x8*)(xb + ii.x + cb);
        const f16x8 b00 = *(const f16x8*)(xb + ii.x + cb + 64);
        const f16x8 a01 = *(const f16x8*)(xb + ii.y + cb);
        const f16x8 b01 = *(const f16x8*)(xb + ii.y + cb + 64);
        const f16x8 a10 = *(const f16x8*)(xb + ii.z + cb);
        const f16x8 b10 = *(const f16x8*)(xb + ii.z + cb + 64);
        const f16x8 a11 = *(const f16x8*)(xb + ii.w + cb);
        const f16x8 b11 = *(const f16x8*)(xb + ii.w + cb + 64);
        f16x8 sa = a00 * wA[0];
        sa += a01 * wA[1];
        sa += a10 * wB[0];
        sa += a11 * wB[1];
        f16x8 sb = b00 * wA[0];
        sb += b01 * wA[1];
        sb += b10 * wB[0];
        sb += b11 * wB[1];
        *(f16x8*)&Abuf[buf][pl * 64 + ((c4 ^ p7) * 8)]       = sa;
        *(f16x8*)&Abuf[buf][pl * 64 + (((4 + c4) ^ p7) * 8)] = sb;
    };

    auto mma_tap = [&](int tap, int buf) {
        #pragma unroll
        for (int sl = 0; sl < 2; sl++) {
            const f16x8 b = __builtin_bit_cast(f16x8, bfrag[tap * 2 + sl]);
            #pragma unroll
            for (int mt = 0; mt < 4; mt++) {
                const int r = mt * 16 + n16;
                const int slot = (sl * 4 + quad) ^ (n16 & 7);
                const f16x8 a = *(const f16x8*)&Abuf[buf][r * 64 + slot * 8];
                acc[mt] = __builtin_amdgcn_mfma_f32_16x16x32_f16(a, b, acc[mt], 0, 0, 0);
            }
        }
    };

    __syncthreads();           // setup visible
    build(0, 0);
    __syncthreads();
    for (int tap = 0; tap < KTAP; tap++) {
        if (tap < KTAP - 1) build(tap + 1, (tap + 1) & 1);
        mma_tap(tap, tap & 1);
        __syncthreads();
    }

    // Epilogue: D col = n16 (out channel), row = quad*4 + reg (pixel)
    const int o = wid * 16 + n16;
    #pragma unroll
    for (int mt = 0; mt < 4; mt++) {
        float4 v = make_float4(acc[mt].x, acc[mt].y, acc[mt].z, acc[mt].w);
        float* dst = out + ((size_t)(n * CCH + o)) * HW + px0 + mt * 16 + quad * 4;
        *(float4*)dst = v;
    }
}

extern "C" void kernel_launch(void* const* d_in, const int* in_sizes, int n_in,
                              void* d_out, int out_size, void* d_ws, size_t ws_size,
                              hipStream_t stream) {
    const float* x      = (const float*)d_in[0];   // [8,64,128,128]
    const float* offset = (const float*)d_in[1];   // [8,18,128,128]
    const float* weight = (const float*)d_in[2];   // [64,64,3,3]
    float* out = (float*)d_out;                    // [8,64,128,128]

    unsigned char* ws = (unsigned char*)d_ws;
    uint4*        bq   = (uint4*)ws;                        // 73728 B
    unsigned int* xt32 = (unsigned int*)(ws + 131072);      // 8 MB (f16 NHWC)
    const unsigned short* xt = (const unsigned short*)xt32;

    prep_kernel<<<2049, 256, 0, stream>>>(x, weight, xt32, bq);
    deform_mfma<<<2048, 256, 0, stream>>>(xt, offset, bq, out);
}

// Round 4
// 135.011 us; speedup vs baseline: 1.1977x; 1.1977x over previous
//
#include <hip/hip_runtime.h>
#include <hip/hip_bf16.h>

// Problem constants
#define NB    8
#define CCH   64      // CIN = COUT = 64
#define HH    128
#define WW    128
#define KTAP  9
#define HW    (HH * WW)            // 16384
#define KSTEPS 18                  // 576 / 32

typedef _Float16 f16x8 __attribute__((ext_vector_type(8)));
typedef _Float16 f16x2 __attribute__((ext_vector_type(2)));
typedef __attribute__((ext_vector_type(4))) float f32x4;

// RNE f32 pair -> packed f16x2 (as uint)
__device__ inline unsigned int pack_f16(float a, float b) {
    f16x2 h;
    h[0] = (_Float16)a;   // v_cvt_f16_f32 (RNE)
    h[1] = (_Float16)b;
    return __builtin_bit_cast(unsigned int, h);
}

__device__ inline f16x8 as_f16x8(uint4 u) { return __builtin_bit_cast(f16x8, u); }

// ---------- K1: maxabs(w) -> atomicMax (ws pre-zeroed by memsetAsync) ----------
__global__ __launch_bounds__(256) void maxabs_kernel(const float* __restrict__ w,
                                                     unsigned int* __restrict__ out) {
    unsigned int m = 0;
    int i = blockIdx.x * 1024 + threadIdx.x;   // 36 blocks cover 36864
    #pragma unroll
    for (int r = 0; r < 4; r++) {
        m = max(m, __float_as_uint(w[i]) & 0x7fffffffu);
        i += 256;
    }
    #pragma unroll
    for (int off = 32; off > 0; off >>= 1)
        m = max(m, (unsigned int)__shfl_down(m, off));
    if ((threadIdx.x & 63) == 0) atomicMax(out, m);
}

// ---------- K2: quantize + swizzle weights into MFMA B-fragment order (f16) ----------
__global__ __launch_bounds__(256) void quant_frag_kernel(const float* __restrict__ w,
                                                         const unsigned int* __restrict__ maxabs_u,
                                                         uint4* __restrict__ bq) {
    int rec = blockIdx.x * 256 + threadIdx.x;    // 0..4607
    if (rec >= 4608) return;
    float m = __uint_as_float(maxabs_u[0]);
    const float scale = fmaxf(m, 1e-8f) / 127.f;
    const float inv_scale = 1.f / scale;
    int nt  = rec / (KSTEPS * 64);
    int rem = rec - nt * (KSTEPS * 64);
    int s    = rem >> 6;
    int lane = rem & 63;
    int quad = lane >> 4, n16 = lane & 15;
    int o = nt * 16 + n16;
    unsigned int u[4];
    #pragma unroll
    for (int jj = 0; jj < 4; jj++) {
        float q[2];
        #pragma unroll
        for (int h = 0; h < 2; h++) {
            int k   = s * 32 + quad * 8 + 2 * jj + h;
            int c   = k & 63;
            int tap = k >> 6;
            float v  = w[(o * CCH + c) * KTAP + tap];
            float qq = rintf(v * inv_scale);          // RNE = jnp.round
            q[h] = fminf(fmaxf(qq, -128.f), 127.f) * scale;
        }
        u[jj] = pack_f16(q[0], q[1]);
    }
    bq[rec] = make_uint4(u[0], u[1], u[2], u[3]);
}

// ---------- K3: transpose x NCHW f32 -> xt NHWC f16 ----------
__global__ __launch_bounds__(256) void transpose_kernel(const float* __restrict__ x,
                                                        unsigned int* __restrict__ xt32) {
    __shared__ float tile[64 * 65];
    const int t = threadIdx.x;
    const int n = blockIdx.x >> 8;
    const int pbase = (blockIdx.x & 255) * 64;
    #pragma unroll
    for (int i = 0; i < 4; i++) {
        int idx = i * 256 + t;
        int c = idx >> 4, f4 = idx & 15;
        float4 v = *(const float4*)&x[((size_t)(n * CCH + c)) * HW + pbase + f4 * 4];
        float* d = &tile[c * 65 + f4 * 4];
        d[0] = v.x; d[1] = v.y; d[2] = v.z; d[3] = v.w;
    }
    __syncthreads();
    const int px = t >> 2, c4 = t & 3;
    float f[16];
    #pragma unroll
    for (int j = 0; j < 16; j++) f[j] = tile[(c4 * 16 + j) * 65 + px];
    unsigned int o8[8];
    #pragma unroll
    for (int i = 0; i < 8; i++) o8[i] = pack_f16(f[2 * i], f[2 * i + 1]);
    uint4* dst = (uint4*)&xt32[((size_t)(n * HW + pbase + px)) * 32 + c4 * 8];
    dst[0] = make_uint4(o8[0], o8[1], o8[2], o8[3]);
    dst[1] = make_uint4(o8[4], o8[5], o8[6], o8[7]);
}

// ---------- K4: fused deformable-sample + MFMA GEMM (software-pipelined) ----------
// Block = 64 pixels x 64 out-channels; wave w = 16-out-channel slab.
__global__ __launch_bounds__(256) void deform_mfma(const unsigned short* __restrict__ xt,
                                                   const float* __restrict__ offset,
                                                   const uint4* __restrict__ bq,
                                                   float* __restrict__ out) {
    __shared__ uint4 SIdx[576];            // per (tap,px): 4 corner byte-offsets
    __shared__ uint2 SW[576];              // per (tap,px): packed f16 weights
    __shared__ _Float16 Abuf[2][64 * 64];  // double-buffered A tile, XOR-swizzled

    const int t    = threadIdx.x;
    const int wid  = t >> 6;
    const int lane = t & 63;
    const int quad = lane >> 4, n16 = lane & 15;
    const int bid  = blockIdx.x;
    const int n    = bid & 7;                 // image -> XCD swizzle
    const int px0  = (bid >> 3) * 64;
    const int pl   = t >> 2;                  // pixel within tile
    const int c4   = t & 3;                   // channel chunk id

    const char* xb = (const char*)(xt + (size_t)n * HW * CCH);
    const float* offn = offset + (size_t)n * 2 * KTAP * HW;

    // Preload this wave's B slab
    uint4 bfrag[KSTEPS];
    #pragma unroll
    for (int s = 0; s < KSTEPS; s++)
        bfrag[s] = bq[(wid * KSTEPS + s) * 64 + lane];

    // ---- setup: one task per (tap, pixel) ----
    for (int u = t; u < 576; u += 256) {
        const int tap = u >> 6, p = u & 63;
        const int ppx = px0 + p;
        const int ho = ppx >> 7, wo = ppx & 127;
        const int ky = tap / 3, kx = tap - 3 * ky;
        const float py  = (float)(ho - 1 + ky) + offn[(2 * tap) * HW + ppx];
        const float pxf = (float)(wo - 1 + kx) + offn[(2 * tap + 1) * HW + ppx];
        const float fy = floorf(py), fx = floorf(pxf);
        const int y0 = (int)fy, x0 = (int)fx;
        const float dy = py - fy, dx = pxf - fx;
        const int y1 = y0 + 1, x1 = x0 + 1;
        const bool vy0 = (y0 >= 0) && (y0 < HH);
        const bool vy1 = (y1 >= 0) && (y1 < HH);
        const bool vx0 = (x0 >= 0) && (x0 < WW);
        const bool vx1 = (x1 >= 0) && (x1 < WW);
        const int y0c = min(max(y0, 0), HH - 1);
        const int y1c = min(max(y1, 0), HH - 1);
        const int x0c = min(max(x0, 0), WW - 1);
        const int x1c = min(max(x1, 0), WW - 1);
        const float w00 = (1.f - dy) * (1.f - dx) * ((vy0 && vx0) ? 1.f : 0.f);
        const float w01 = (1.f - dy) * dx         * ((vy0 && vx1) ? 1.f : 0.f);
        const float w10 = dy * (1.f - dx)         * ((vy1 && vx0) ? 1.f : 0.f);
        const float w11 = dy * dx                 * ((vy1 && vx1) ? 1.f : 0.f);
        SIdx[u] = make_uint4((unsigned)((y0c * WW + x0c) * 128),
                             (unsigned)((y0c * WW + x1c) * 128),
                             (unsigned)((y1c * WW + x0c) * 128),
                             (unsigned)((y1c * WW + x1c) * 128));
        SW[u] = make_uint2(pack_f16(w00, w01), pack_f16(w10, w11));
    }

    f32x4 acc[4];
    #pragma unroll
    for (int mt = 0; mt < 4; mt++) acc[mt] = (f32x4){0.f, 0.f, 0.f, 0.f};

    // chunk A = channels [c4*8, +8), chunk B = channels [32+c4*8, +8):
    // both 16B loads of a corner sit in the same 128B pixel row.
    const int cb = c4 * 16;
    const int p7 = pl & 7;

    uint4 r[8];   // prefetched corner data for the *current* tap
    auto issue = [&](int tap) {
        const uint4 ii = SIdx[tap * 64 + pl];
        r[0] = *(const uint4*)(xb + ii.x + cb);
        r[1] = *(const uint4*)(xb + ii.x + cb + 64);
        r[2] = *(const uint4*)(xb + ii.y + cb);
        r[3] = *(const uint4*)(xb + ii.y + cb + 64);
        r[4] = *(const uint4*)(xb + ii.z + cb);
        r[5] = *(const uint4*)(xb + ii.z + cb + 64);
        r[6] = *(const uint4*)(xb + ii.w + cb);
        r[7] = *(const uint4*)(xb + ii.w + cb + 64);
    };
    auto blendwrite = [&](int tap, int buf) {
        const uint2 ww = SW[tap * 64 + pl];
        const f16x2 wA = __builtin_bit_cast(f16x2, ww.x);
        const f16x2 wB = __builtin_bit_cast(f16x2, ww.y);
        f16x8 sa = as_f16x8(r[0]) * wA[0];
        sa += as_f16x8(r[2]) * wA[1];
        sa += as_f16x8(r[4]) * wB[0];
        sa += as_f16x8(r[6]) * wB[1];
        f16x8 sb = as_f16x8(r[1]) * wA[0];
        sb += as_f16x8(r[3]) * wA[1];
        sb += as_f16x8(r[5]) * wB[0];
        sb += as_f16x8(r[7]) * wB[1];
        *(f16x8*)&Abuf[buf][pl * 64 + ((c4 ^ p7) * 8)]       = sa;
        *(f16x8*)&Abuf[buf][pl * 64 + (((4 + c4) ^ p7) * 8)] = sb;
    };
    auto mma_tap = [&](int tap, int buf) {
        #pragma unroll
        for (int sl = 0; sl < 2; sl++) {
            const f16x8 b = __builtin_bit_cast(f16x8, bfrag[tap * 2 + sl]);
            #pragma unroll
            for (int mt = 0; mt < 4; mt++) {
                const int rr = mt * 16 + n16;
                const int slot = (sl * 4 + quad) ^ (n16 & 7);
                const f16x8 a = *(const f16x8*)&Abuf[buf][rr * 64 + slot * 8];
                acc[mt] = __builtin_amdgcn_mfma_f32_16x16x32_f16(a, b, acc[mt], 0, 0, 0);
            }
        }
    };

    __syncthreads();           // setup visible
    issue(0);                  // prefetch tap 0
    #pragma unroll
    for (int tap = 0; tap < KTAP; tap++) {
        blendwrite(tap, tap & 1);          // consumes r (waits only its own loads)
        if (tap < KTAP - 1) issue(tap + 1); // next tap's gathers fly across barrier+MFMA
        __syncthreads();
        mma_tap(tap, tap & 1);
    }

    // Epilogue: D col = n16 (out channel), row = quad*4 + reg (pixel)
    const int o = wid * 16 + n16;
    #pragma unroll
    for (int mt = 0; mt < 4; mt++) {
        float4 v = make_float4(acc[mt].x, acc[mt].y, acc[mt].z, acc[mt].w);
        float* dst = out + ((size_t)(n * CCH + o)) * HW + px0 + mt * 16 + quad * 4;
        *(float4*)dst = v;
    }
}

extern "C" void kernel_launch(void* const* d_in, const int* in_sizes, int n_in,
                              void* d_out, int out_size, void* d_ws, size_t ws_size,
                              hipStream_t stream) {
    const float* x      = (const float*)d_in[0];   // [8,64,128,128]
    const float* offset = (const float*)d_in[1];   // [8,18,128,128]
    const float* weight = (const float*)d_in[2];   // [64,64,3,3]
    float* out = (float*)d_out;                    // [8,64,128,128]

    unsigned char* ws = (unsigned char*)d_ws;
    unsigned int* maxabs_u = (unsigned int*)ws;             // 4 B
    uint4*        bq   = (uint4*)(ws + 1024);               // 73728 B
    unsigned int* xt32 = (unsigned int*)(ws + 131072);      // 8 MB (f16 NHWC)
    const unsigned short* xt = (const unsigned short*)xt32;

    hipMemsetAsync(maxabs_u, 0, 4, stream);
    maxabs_kernel<<<36, 256, 0, stream>>>(weight, maxabs_u);
    quant_frag_kernel<<<18, 256, 0, stream>>>(weight, maxabs_u, bq);
    transpose_kernel<<<2048, 256, 0, stream>>>(x, xt32);
    deform_mfma<<<2048, 256, 0, stream>>>(xt, offset, bq, out);
}

// Round 5
// 132.175 us; speedup vs baseline: 1.2234x; 1.0215x over previous
//
#include <hip/hip_runtime.h>
#include <hip/hip_bf16.h>

// Problem constants
#define NB    8
#define CCH   64      // CIN = COUT = 64
#define HH    128
#define WW    128
#define KTAP  9
#define HW    (HH * WW)            // 16384
#define KSTEPS 18                  // 576 / 32
#define NW    36864                // weight elements

typedef _Float16 f16x8 __attribute__((ext_vector_type(8)));
typedef _Float16 f16x2 __attribute__((ext_vector_type(2)));
typedef __attribute__((ext_vector_type(4))) float f32x4;

// RNE f32 pair -> packed f16x2 (as uint)
__device__ inline unsigned int pack_f16(float a, float b) {
    f16x2 h;
    h[0] = (_Float16)a;   // v_cvt_f16_f32 (RNE)
    h[1] = (_Float16)b;
    return __builtin_bit_cast(unsigned int, h);
}

__device__ inline f16x8 as_f16x8(uint4 u) { return __builtin_bit_cast(f16x8, u); }

// ---------- K1: transpose x NCHW f32 -> xt NHWC f16 (blocks 0..2047)
//             + weight quant into MFMA B frags (blocks 2048..2065, redundant maxabs)
__global__ __launch_bounds__(256) void prep_kernel(const float* __restrict__ x,
                                                   const float* __restrict__ w,
                                                   unsigned int* __restrict__ xt32,
                                                   uint4* __restrict__ bq) {
    __shared__ float tile[64 * 65];
    const int t = threadIdx.x;
    const int bid = blockIdx.x;

    if (bid < 2048) {
        // ---- transpose 64 channels x 64 pixels ----
        const int n = bid >> 8;
        const int pbase = (bid & 255) * 64;
        #pragma unroll
        for (int i = 0; i < 4; i++) {
            int idx = i * 256 + t;
            int c = idx >> 4, f4 = idx & 15;
            float4 v = *(const float4*)&x[((size_t)(n * CCH + c)) * HW + pbase + f4 * 4];
            float* d = &tile[c * 65 + f4 * 4];
            d[0] = v.x; d[1] = v.y; d[2] = v.z; d[3] = v.w;
        }
        __syncthreads();
        const int px = t >> 2, c4 = t & 3;
        float f[16];
        #pragma unroll
        for (int j = 0; j < 16; j++) f[j] = tile[(c4 * 16 + j) * 65 + px];
        unsigned int o8[8];
        #pragma unroll
        for (int i = 0; i < 8; i++) o8[i] = pack_f16(f[2 * i], f[2 * i + 1]);
        uint4* dst = (uint4*)&xt32[((size_t)(n * HW + pbase + px)) * 32 + c4 * 8];
        dst[0] = make_uint4(o8[0], o8[1], o8[2], o8[3]);
        dst[1] = make_uint4(o8[4], o8[5], o8[6], o8[7]);
    } else {
        // ---- each of 18 blocks: full maxabs (parallel, redundant) + 256 recs ----
        float m0 = 0.f, m1 = 0.f, m2 = 0.f, m3 = 0.f;
        for (int i = t; i < NW; i += 1024) {       // 36 iters, 4-way ILP
            m0 = fmaxf(m0, fabsf(w[i]));
            m1 = fmaxf(m1, fabsf(w[i + 256]));
            m2 = fmaxf(m2, fabsf(w[i + 512]));
            m3 = fmaxf(m3, fabsf(w[i + 768]));
        }
        float m = fmaxf(fmaxf(m0, m1), fmaxf(m2, m3));
        #pragma unroll
        for (int off = 32; off > 0; off >>= 1)
            m = fmaxf(m, __shfl_down(m, off));
        if ((t & 63) == 0) tile[t >> 6] = m;
        __syncthreads();
        m = fmaxf(fmaxf(tile[0], tile[1]), fmaxf(tile[2], tile[3]));
        const float scale = fmaxf(m, 1e-8f) / 127.f;
        const float inv_scale = 1.f / scale;

        const int rec = (bid - 2048) * 256 + t;    // 0..4607
        int nt  = rec / (KSTEPS * 64);
        int rem = rec - nt * (KSTEPS * 64);
        int s    = rem >> 6;
        int lane = rem & 63;
        int quad = lane >> 4, n16 = lane & 15;
        int o = nt * 16 + n16;
        unsigned int u[4];
        #pragma unroll
        for (int jj = 0; jj < 4; jj++) {
            float q[2];
            #pragma unroll
            for (int h = 0; h < 2; h++) {
                int k   = s * 32 + quad * 8 + 2 * jj + h;
                int c   = k & 63;
                int tap = k >> 6;
                float v  = w[(o * CCH + c) * KTAP + tap];
                float qq = rintf(v * inv_scale);          // RNE = jnp.round
                q[h] = fminf(fmaxf(qq, -128.f), 127.f) * scale;
            }
            u[jj] = pack_f16(q[0], q[1]);
        }
        bq[rec] = make_uint4(u[0], u[1], u[2], u[3]);
    }
}

// ---------- K2: fused deformable-sample + MFMA GEMM (deep-pipelined) ----------
// Block = 64 pixels x 64 out-channels; wave w = 16-out-channel slab.
__global__ __launch_bounds__(256) void deform_mfma(const unsigned short* __restrict__ xt,
                                                   const float* __restrict__ offset,
                                                   const uint4* __restrict__ bq,
                                                   float* __restrict__ out) {
    __shared__ unsigned int SC[576];       // packed clamped corners per (tap,px)
    __shared__ uint2 SW[576];              // packed f16 bilinear weights
    __shared__ _Float16 Abuf[2][64 * 64];  // double-buffered A tile, XOR-swizzled

    const int t    = threadIdx.x;
    const int wid  = t >> 6;
    const int lane = t & 63;
    const int quad = lane >> 4, n16 = lane & 15;
    const int bid  = blockIdx.x;
    const int n    = bid & 7;                 // image -> XCD swizzle
    const int px0  = (bid >> 3) * 64;
    const int pl   = t >> 2;                  // pixel within tile
    const int c4   = t & 3;                   // channel chunk id

    const char* xb = (const char*)(xt + (size_t)n * HW * CCH);
    const float* offn = offset + (size_t)n * 2 * KTAP * HW;
    const uint4* bqw = bq + (size_t)wid * KSTEPS * 64 + lane;

    // ---- setup: one task per (tap, pixel) ----
    for (int u = t; u < 576; u += 256) {
        const int tap = u >> 6, p = u & 63;
        const int ppx = px0 + p;
        const int ho = ppx >> 7, wo = ppx & 127;
        const int ky = tap / 3, kx = tap - 3 * ky;
        const float py  = (float)(ho - 1 + ky) + offn[(2 * tap) * HW + ppx];
        const float pxf = (float)(wo - 1 + kx) + offn[(2 * tap + 1) * HW + ppx];
        const float fy = floorf(py), fx = floorf(pxf);
        const int y0 = (int)fy, x0 = (int)fx;
        const float dy = py - fy, dx = pxf - fx;
        const int y1 = y0 + 1, x1 = x0 + 1;
        const bool vy0 = (y0 >= 0) && (y0 < HH);
        const bool vy1 = (y1 >= 0) && (y1 < HH);
        const bool vx0 = (x0 >= 0) && (x0 < WW);
        const bool vx1 = (x1 >= 0) && (x1 < WW);
        const int y0c = min(max(y0, 0), HH - 1);
        const int y1c = min(max(y1, 0), HH - 1);
        const int x0c = min(max(x0, 0), WW - 1);
        const int x1c = min(max(x1, 0), WW - 1);
        const float w00 = (1.f - dy) * (1.f - dx) * ((vy0 && vx0) ? 1.f : 0.f);
        const float w01 = (1.f - dy) * dx         * ((vy0 && vx1) ? 1.f : 0.f);
        const float w10 = dy * (1.f - dx)         * ((vy1 && vx0) ? 1.f : 0.f);
        const float w11 = dy * dx                 * ((vy1 && vx1) ? 1.f : 0.f);
        SC[u] = (unsigned)(y0c | (x0c << 7) | (y1c << 14) | (x1c << 21));
        SW[u] = make_uint2(pack_f16(w00, w01), pack_f16(w10, w11));
    }

    f32x4 acc[4];
    #pragma unroll
    for (int mt = 0; mt < 4; mt++) acc[mt] = (f32x4){0.f, 0.f, 0.f, 0.f};

    const int cb = c4 * 16;       // byte offset of chunk A within 128B pixel row
    const int p7 = pl & 7;

    uint4 rbuf[2][8];             // double-buffered corner data
    uint4 bbuf[2][2];             // double-buffered B fragments (per tap)

    auto issue = [&](int tap, int b) {
        // B first (so blend's rbuf wait also drains it)
        bbuf[b][0] = bqw[(tap * 2 + 0) * 64];
        bbuf[b][1] = bqw[(tap * 2 + 1) * 64];
        const unsigned int cc = SC[tap * 64 + pl];
        const int y0b = (int)(cc & 127) << 14;
        const int x0b = (int)((cc >> 7) & 127) << 7;
        const int y1b = (int)((cc >> 14) & 127) << 14;
        const int x1b = (int)(cc >> 21) << 7;
        const char* q00 = xb + (y0b | x0b) + cb;
        const char* q01 = xb + (y0b | x1b) + cb;
        const char* q10 = xb + (y1b | x0b) + cb;
        const char* q11 = xb + (y1b | x1b) + cb;
        rbuf[b][0] = *(const uint4*)q00; rbuf[b][1] = *(const uint4*)(q00 + 64);
        rbuf[b][2] = *(const uint4*)q01; rbuf[b][3] = *(const uint4*)(q01 + 64);
        rbuf[b][4] = *(const uint4*)q10; rbuf[b][5] = *(const uint4*)(q10 + 64);
        rbuf[b][6] = *(const uint4*)q11; rbuf[b][7] = *(const uint4*)(q11 + 64);
    };

    auto blend = [&](int tap, int b) {
        const uint2 ww = SW[tap * 64 + pl];
        const f16x2 wA = __builtin_bit_cast(f16x2, ww.x);   // w00, w01
        const f16x2 wB = __builtin_bit_cast(f16x2, ww.y);   // w10, w11
        f16x8 sa = as_f16x8(rbuf[b][0]) * wA[0];
        sa += as_f16x8(rbuf[b][2]) * wA[1];
        sa += as_f16x8(rbuf[b][4]) * wB[0];
        sa += as_f16x8(rbuf[b][6]) * wB[1];
        f16x8 sb = as_f16x8(rbuf[b][1]) * wA[0];
        sb += as_f16x8(rbuf[b][3]) * wA[1];
        sb += as_f16x8(rbuf[b][5]) * wB[0];
        sb += as_f16x8(rbuf[b][7]) * wB[1];
        *(f16x8*)&Abuf[b][pl * 64 + ((c4 ^ p7) * 8)]       = sa;
        *(f16x8*)&Abuf[b][pl * 64 + (((4 + c4) ^ p7) * 8)] = sb;
    };

    auto mma_tap = [&](int tap, int b) {
        #pragma unroll
        for (int sl = 0; sl < 2; sl++) {
            const f16x8 bf = __builtin_bit_cast(f16x8, bbuf[b][sl]);
            #pragma unroll
            for (int mt = 0; mt < 4; mt++) {
                const int rr = mt * 16 + n16;
                const int slot = (sl * 4 + quad) ^ (n16 & 7);
                const f16x8 a = *(const f16x8*)&Abuf[b][rr * 64 + slot * 8];
                acc[mt] = __builtin_amdgcn_mfma_f32_16x16x32_f16(a, bf, acc[mt], 0, 0, 0);
            }
        }
    };

    __syncthreads();           // setup visible
    issue(0, 0);
    #pragma unroll
    for (int tap = 0; tap < KTAP; tap++) {
        if (tap < KTAP - 1) issue(tap + 1, (tap + 1) & 1);  // full-iteration distance
        blend(tap, tap & 1);
        __syncthreads();
        mma_tap(tap, tap & 1);
    }

    // Epilogue: D col = n16 (out channel), row = quad*4 + reg (pixel)
    const int o = wid * 16 + n16;
    #pragma unroll
    for (int mt = 0; mt < 4; mt++) {
        float4 v = make_float4(acc[mt].x, acc[mt].y, acc[mt].z, acc[mt].w);
        float* dst = out + ((size_t)(n * CCH + o)) * HW + px0 + mt * 16 + quad * 4;
        *(float4*)dst = v;
    }
}

extern "C" void kernel_launch(void* const* d_in, const int* in_sizes, int n_in,
                              void* d_out, int out_size, void* d_ws, size_t ws_size,
                              hipStream_t stream) {
    const float* x      = (const float*)d_in[0];   // [8,64,128,128]
    const float* offset = (const float*)d_in[1];   // [8,18,128,128]
    const float* weight = (const float*)d_in[2];   // [64,64,3,3]
    float* out = (float*)d_out;                    // [8,64,128,128]

    unsigned char* ws = (unsigned char*)d_ws;
    uint4*        bq   = (uint4*)ws;                        // 73728 B
    unsigned int* xt32 = (unsigned int*)(ws + 131072);      // 8 MB (f16 NHWC)
    const unsigned short* xt = (const unsigned short*)xt32;

    prep_kernel<<<2048 + 18, 256, 0, stream>>>(x, weight, xt32, bq);
    deform_mfma<<<2048, 256, 0, stream>>>(xt, offset, bq, out);
}